// Round 4
// baseline (92.721 us; speedup 1.0000x reference)
//
#include <hip/hip_runtime.h>

typedef __attribute__((ext_vector_type(4))) float f32x4;
typedef __attribute__((ext_vector_type(8))) short bf16x8;

#define NP 4096
#define GC 32                  // fine sort grid GC x GC (0.625 m cells)
#define NFC (GC * GC)          // 1024 fine cells
#define WR 8                   // window radius in fine cells (covers +-4.8m)
#define IB 4                   // peds per pool block (1 per wave)

__device__ __forceinline__ unsigned short f2bf(float f) {
  unsigned int u = __float_as_uint(f);
  u = u + 0x7FFFu + ((u >> 16) & 1u);   // round-to-nearest-even
  return (unsigned short)(u >> 16);
}

__global__ __launch_bounds__(256) void prep_kernel(
    const float2* __restrict__ pos, const float2* __restrict__ past,
    float4* __restrict__ posvel, int* __restrict__ cellid) {
  int i = blockIdx.x * 256 + threadIdx.x;
  float2 p = pos[i];
  float2 q = past[i];
  posvel[i] = make_float4(p.x, p.y, p.x - q.x, p.y - q.y);
  int cx = (int)(p.x * (GC / 20.0f));
  int cy = (int)(p.y * (GC / 20.0f));
  cx = min(max(cx, 0), GC - 1);
  cy = min(max(cy, 0), GC - 1);
  cellid[i] = cx * GC + cy;
}

// One block, 1024 threads: histogram of cellid + Hillis-Steele scan ->
// cellstart[1025] (exclusive) and cursor[1024] (scatter cursors).
__global__ __launch_bounds__(1024) void setup_kernel(
    const int* __restrict__ cellid, int* __restrict__ cellstart,
    int* __restrict__ cursor) {
  __shared__ int hist[NFC];
  const int tid = threadIdx.x;
  hist[tid] = 0;
  __syncthreads();
  for (int p = tid; p < NP; p += 1024) atomicAdd(&hist[cellid[p]], 1);
  __syncthreads();
  const int myc = hist[tid];
  __syncthreads();
  for (int off = 1; off < NFC; off <<= 1) {
    int u = (tid >= off) ? hist[tid - off] : 0;
    __syncthreads();
    hist[tid] += u;
    __syncthreads();
  }
  const int excl = hist[tid] - myc;
  cellstart[tid] = excl;
  cursor[tid] = excl;
  if (tid == NFC - 1) cellstart[NFC] = hist[tid];
}

__global__ __launch_bounds__(256) void scatter_kernel(
    const float4* __restrict__ posvel, const int* __restrict__ cellid,
    int* __restrict__ cursor, float4* __restrict__ sorted,
    int* __restrict__ orig) {
  int p = blockIdx.x * 256 + threadIdx.x;
  int dst = atomicAdd(&cursor[cellid[p]], 1);
  sorted[dst] = posvel[p];
  orig[dst] = p;
}

// Block = IB sorted peds, wave w owns ped isrt = blockIdx*IB + w.
// Wave walks only the 17-stripe fine-cell window of its ped (~1160 js).
// Stripe prefix table cached in registers via shfl broadcast; locate is a
// fully-unrolled select chain (compile-time indices -> stays in VGPRs).
// Self-pair lands in cell 136 with vals (0,0), cnt 1; compensated in epilogue.
__global__ __launch_bounds__(256, 4) void pool_kernel(
    const float4* __restrict__ sorted, const int* __restrict__ orig,
    const int* __restrict__ cellstart, unsigned short* __restrict__ gridws) {
  __shared__ float acc[IB][256 * 3];
  const int tid = threadIdx.x;
  const int lane = tid & 63;
  const int w = tid >> 6;
  const int isrt = blockIdx.x * IB + w;

  for (int idx = tid; idx < IB * 256 * 3; idx += 256) ((float*)acc)[idx] = 0.0f;

  const float4 pvi = sorted[isrt];
  int cxi = (int)(pvi.x * (GC / 20.0f));
  int cyi = (int)(pvi.y * (GC / 20.0f));
  cxi = min(max(cxi, 0), GC - 1);
  cyi = min(max(cyi, 0), GC - 1);

  // lanes 0..16 gather their stripe's [start, len)
  int s = 0, len = 0;
  if (lane < 17) {
    int cx = cxi - WR + lane;
    if (cx >= 0 && cx < GC) {
      int cy0 = max(cyi - WR, 0), cy1 = min(cyi + WR, GC - 1);
      s = cellstart[cx * GC + cy0];
      len = cellstart[cx * GC + cy1 + 1] - s;
    }
  }
  // wave inclusive scan of len over lanes
  int cum = len;
#pragma unroll
  for (int d = 1; d < 32; d <<= 1) {
    int u = __shfl_up(cum, d);
    if (lane >= d) cum += u;
  }
  const int baseval = s - (cum - len);  // start - exclusive_prefix

  int cums[16], bases[17];
#pragma unroll
  for (int k = 0; k < 16; ++k) cums[k] = __shfl(cum, k);
#pragma unroll
  for (int k = 0; k < 17; ++k) bases[k] = __shfl(baseval, k);
  const int T = __shfl(cum, 16);

  __syncthreads();  // acc zeroed by all threads

  float* accw = acc[w];

  auto locate = [&](int g) {
    int b = bases[0];
#pragma unroll
    for (int k = 1; k < 17; ++k) b = (g >= cums[k - 1]) ? bases[k] : b;
    return b + g;
  };

  auto process = [&](int g, float4 pvj) {
    float rx = pvj.x - pvi.x;
    float ry = pvj.y - pvi.y;
    // exact IEEE fp32 division to match numpy floor(rel/0.6 + 8)
    float fx = floorf(rx / 0.6f + 8.0f);
    float fy = floorf(ry / 0.6f + 8.0f);
    int ix = (int)fx;
    int iy = (int)fy;
    if ((g < T) & ((unsigned)ix < 16u) & ((unsigned)iy < 16u)) {
      float* p = &accw[((ix << 4) + iy) * 3];
      atomicAdd(p + 0, pvj.z - pvi.z);
      atomicAdd(p + 1, pvj.w - pvi.w);
      atomicAdd(p + 2, 1.0f);
    }
  };

  for (int g0 = 0; g0 < T; g0 += 128) {
    int gA = g0 + lane;
    int gB = g0 + 64 + lane;
    int jA = (gA < T) ? locate(gA) : isrt;
    int jB = (gB < T) ? locate(gB) : isrt;
    float4 a = sorted[jA];          // two independent loads in flight
    float4 b = sorted[jB];
    process(gA, a);
    process(gB, b);
  }
  __syncthreads();

  // epilogue: wave w writes its ped's 256 cells (4 packed u32 per lane)
  const int io = orig[isrt];
#pragma unroll
  for (int r = 0; r < 4; ++r) {
    int cell = r * 64 + lane;
    float sx = accw[cell * 3 + 0];
    float sy = accw[cell * 3 + 1];
    float cn = accw[cell * 3 + 2] - ((cell == 136) ? 1.0f : 0.0f);
    float d = fmaxf(cn, 1.0f);
    unsigned int packed =
        ((unsigned int)f2bf(sy / d) << 16) | (unsigned int)f2bf(sx / d);
    *(unsigned int*)&gridws[(size_t)io * 512 + cell * 2] = packed;
  }
}

// C[4096][256] = relu(A[4096][512](bf16) * W[256][512]^T + b), fp32 out.
__global__ __launch_bounds__(256) void gemm_kernel(
    const unsigned short* __restrict__ A, const float* __restrict__ W,
    const float* __restrict__ bias, float* __restrict__ out) {
  __shared__ unsigned short As[64][40];
  __shared__ unsigned short Bs[64][40];
  const int tid = threadIdx.x;
  const int lane = tid & 63;
  const int wid = tid >> 6;
  const int wr = wid >> 1;
  const int wc = wid & 1;
  const int mbase = blockIdx.y * 64;
  const int nbase = blockIdx.x * 64;
  const int srow = tid >> 2;
  const int skq = tid & 3;

  f32x4 acc00 = {0.f, 0.f, 0.f, 0.f};
  f32x4 acc01 = {0.f, 0.f, 0.f, 0.f};
  f32x4 acc10 = {0.f, 0.f, 0.f, 0.f};
  f32x4 acc11 = {0.f, 0.f, 0.f, 0.f};

  const int lrow = lane & 15;
  const int lk = (lane >> 4) * 8;

  for (int kb = 0; kb < 512; kb += 32) {
    __syncthreads();
    *(bf16x8*)&As[srow][skq * 8] =
        *(const bf16x8*)&A[(size_t)(mbase + srow) * 512 + kb + skq * 8];
    const float* wp = &W[(size_t)(nbase + srow) * 512 + kb + skq * 8];
    float4 w0 = *(const float4*)wp;
    float4 w1 = *(const float4*)(wp + 4);
    bf16x8 bv;
    bv[0] = (short)f2bf(w0.x); bv[1] = (short)f2bf(w0.y);
    bv[2] = (short)f2bf(w0.z); bv[3] = (short)f2bf(w0.w);
    bv[4] = (short)f2bf(w1.x); bv[5] = (short)f2bf(w1.y);
    bv[6] = (short)f2bf(w1.z); bv[7] = (short)f2bf(w1.w);
    *(bf16x8*)&Bs[srow][skq * 8] = bv;
    __syncthreads();

    bf16x8 a0 = *(const bf16x8*)&As[wr * 32 + lrow][lk];
    bf16x8 a1 = *(const bf16x8*)&As[wr * 32 + 16 + lrow][lk];
    bf16x8 b0 = *(const bf16x8*)&Bs[wc * 32 + lrow][lk];
    bf16x8 b1 = *(const bf16x8*)&Bs[wc * 32 + 16 + lrow][lk];
    acc00 = __builtin_amdgcn_mfma_f32_16x16x32_bf16(a0, b0, acc00, 0, 0, 0);
    acc01 = __builtin_amdgcn_mfma_f32_16x16x32_bf16(a0, b1, acc01, 0, 0, 0);
    acc10 = __builtin_amdgcn_mfma_f32_16x16x32_bf16(a1, b0, acc10, 0, 0, 0);
    acc11 = __builtin_amdgcn_mfma_f32_16x16x32_bf16(a1, b1, acc11, 0, 0, 0);
  }

  const int row0 = mbase + wr * 32 + (lane >> 4) * 4;
  const int col0 = nbase + wc * 32 + lrow;
#pragma unroll
  for (int ni = 0; ni < 2; ++ni) {
    int col = col0 + ni * 16;
    float bv = bias[col];
    const f32x4* a0p = (ni == 0) ? &acc00 : &acc01;
    const f32x4* a1p = (ni == 0) ? &acc10 : &acc11;
#pragma unroll
    for (int q = 0; q < 4; ++q) {
      float v0 = (*a0p)[q] + bv;
      out[(size_t)(row0 + q) * 256 + col] = fmaxf(v0, 0.0f);
      float v1 = (*a1p)[q] + bv;
      out[(size_t)(row0 + 16 + q) * 256 + col] = fmaxf(v1, 0.0f);
    }
  }
}

extern "C" void kernel_launch(void* const* d_in, const int* in_sizes, int n_in,
                              void* d_out, int out_size, void* d_ws, size_t ws_size,
                              hipStream_t stream) {
  // inputs: 0=h (unused), 1=positions, 2=past_positions, 3=W_emb, 4=b_emb
  const float2* pos = (const float2*)d_in[1];
  const float2* past = (const float2*)d_in[2];
  const float* W = (const float*)d_in[3];
  const float* bias = (const float*)d_in[4];
  float* out = (float*)d_out;

  char* ws = (char*)d_ws;
  float4* posvel = (float4*)ws;                         // 64 KB
  float4* sorted = (float4*)(ws + 64 * 1024);           // 64 KB
  int* cellid = (int*)(ws + 128 * 1024);                // 16 KB
  int* orig = (int*)(ws + 144 * 1024);                  // 16 KB
  int* cellstart = (int*)(ws + 160 * 1024);             // 8 KB (1025 used)
  int* cursor = (int*)(ws + 168 * 1024);                // 8 KB (1024 used)
  unsigned short* gridws = (unsigned short*)(ws + 176 * 1024);  // 4 MB

  prep_kernel<<<NP / 256, 256, 0, stream>>>(pos, past, posvel, cellid);
  setup_kernel<<<1, 1024, 0, stream>>>(cellid, cellstart, cursor);
  scatter_kernel<<<NP / 256, 256, 0, stream>>>(posvel, cellid, cursor, sorted, orig);
  pool_kernel<<<NP / IB, 256, 0, stream>>>(sorted, orig, cellstart, gridws);
  dim3 g(256 / 64, NP / 64);
  gemm_kernel<<<g, 256, 0, stream>>>(gridws, W, bias, out);
}

// Round 5
// 35.865 us; speedup vs baseline: 2.5853x; 2.5853x over previous
//
#include <hip/hip_runtime.h>

typedef __attribute__((ext_vector_type(4))) float f32x4;
typedef __attribute__((ext_vector_type(8))) short bf16x8;

#define NP 4096
#define IB 2

__device__ __forceinline__ unsigned short f2bf(float f) {
  unsigned int u = __float_as_uint(f);
  u = u + 0x7FFFu + ((u >> 16) & 1u);   // round-to-nearest-even
  return (unsigned short)(u >> 16);
}

// Block = IB peds, 256 threads: tx = which ped, ty = j-slot (stride 128).
// Per in-range pair: ONE u64 LDS atomic packing (qx+2^14)<<38 | (qy+2^14)<<12 | 1,
// fixed point scale 2^-11. Field budget: <=2047 hits/ped * 2^15 < 2^26 -> no
// cross-field carry. cnt in low 12 bits (<=4095). Integer accumulation is
// order-independent (deterministic). Self-pair lands in cell 136 with qx=qy=0,
// cnt 1; compensated in the epilogue.
// Cell binning: approx fma (err <=1.1e-5) + exact-IEEE-div fallback when any
// lane is within 1e-4 of an integer boundary -> bit-exact vs numpy.
__global__ __launch_bounds__(256, 8) void pool_kernel(
    const float2* __restrict__ pos, const float2* __restrict__ past,
    unsigned short* __restrict__ gridws) {
  __shared__ unsigned long long acc[IB][256];
  const int tid = threadIdx.x;
  const int tx = tid & (IB - 1);
  const int ty = tid >> 1;          // 0..127
  const int ibase = blockIdx.x * IB;
  const int i = ibase + tx;

  for (int idx = tid; idx < IB * 256 * 2; idx += 256)
    ((unsigned int*)acc)[idx] = 0u;
  __syncthreads();

  const float2 pi = pos[i];
  const float2 qi = past[i];
  const float vix = pi.x - qi.x;
  const float viy = pi.y - qi.y;
  unsigned long long* accp = acc[tx];
  const float inv06 = 1.0f / 0.6f;

  auto process = [&](float2 pj, float2 qj) {
    float rx = pj.x - pi.x;
    float ry = pj.y - pi.y;
    float ax = __builtin_fmaf(rx, inv06, 8.0f);
    float ay = __builtin_fmaf(ry, inv06, 8.0f);
    bool unc = (fabsf(ax - rintf(ax)) < 1e-4f) |
               (fabsf(ay - rintf(ay)) < 1e-4f);
    float fx, fy;
    if (__any(unc)) {
      // exact IEEE fp32 division path to match numpy floor(rel/0.6 + 8)
      fx = floorf(rx / 0.6f + 8.0f);
      fy = floorf(ry / 0.6f + 8.0f);
    } else {
      fx = floorf(ax);
      fy = floorf(ay);
    }
    int ix = (int)fx;
    int iy = (int)fy;
    if (((unsigned)ix < 16u) & ((unsigned)iy < 16u)) {
      float rvx = (pj.x - qj.x) - vix;
      float rvy = (pj.y - qj.y) - viy;
      unsigned int qx = (unsigned int)((int)rintf(rvx * 2048.0f) + 16384);
      unsigned int qy = (unsigned int)((int)rintf(rvy * 2048.0f) + 16384);
      unsigned long long p = ((unsigned long long)qx << 38) |
                             ((unsigned long long)qy << 12) | 1ull;
      atomicAdd(&accp[(ix << 4) + iy], p);
    }
  };

  for (int jo = 0; jo < NP; jo += 512) {
    int j0 = jo + ty;
    float2 p0 = pos[j0];        float2 q0 = past[j0];
    float2 p1 = pos[j0 + 128];  float2 q1 = past[j0 + 128];
    float2 p2 = pos[j0 + 256];  float2 q2 = past[j0 + 256];
    float2 p3 = pos[j0 + 384];  float2 q3 = past[j0 + 384];
    process(p0, q0);
    process(p1, q1);
    process(p2, q2);
    process(p3, q3);
  }
  __syncthreads();

  // epilogue: decode u64, normalize (mean per cell), store bf16 [NP][512]
  const int cell = tid;  // 0..255
  const float selfc = (cell == 136) ? 1.0f : 0.0f;
#pragma unroll
  for (int il = 0; il < IB; ++il) {
    unsigned long long raw = acc[il][cell];
    unsigned int cnt = (unsigned int)(raw & 0xFFFull);
    int sxq = (int)((unsigned int)(raw >> 38)) - (int)(cnt << 14);
    int syq = (int)((unsigned int)((raw >> 12) & 0x3FFFFFFull)) - (int)(cnt << 14);
    float cn = (float)cnt - selfc;
    float d = fmaxf(cn, 1.0f);
    float sx = (float)sxq * (1.0f / 2048.0f);
    float sy = (float)syq * (1.0f / 2048.0f);
    unsigned int packed =
        ((unsigned int)f2bf(sy / d) << 16) | (unsigned int)f2bf(sx / d);
    *(unsigned int*)&gridws[(size_t)(ibase + il) * 512 + cell * 2] = packed;
  }
}

// C[4096][256] = relu(A[4096][512](bf16) * W[256][512]^T + b), fp32 out.
// 64x64 tile per block, 4 waves in 2x2 quadrants, each wave 2x2 MFMA frags.
// LDS rows padded to 40 ushorts (80B): ds_read_b128 2-way conflict (free).
__global__ __launch_bounds__(256) void gemm_kernel(
    const unsigned short* __restrict__ A, const float* __restrict__ W,
    const float* __restrict__ bias, float* __restrict__ out) {
  __shared__ unsigned short As[64][40];
  __shared__ unsigned short Bs[64][40];
  const int tid = threadIdx.x;
  const int lane = tid & 63;
  const int wid = tid >> 6;
  const int wr = wid >> 1;
  const int wc = wid & 1;
  const int mbase = blockIdx.y * 64;
  const int nbase = blockIdx.x * 64;
  const int srow = tid >> 2;
  const int skq = tid & 3;

  f32x4 acc00 = {0.f, 0.f, 0.f, 0.f};
  f32x4 acc01 = {0.f, 0.f, 0.f, 0.f};
  f32x4 acc10 = {0.f, 0.f, 0.f, 0.f};
  f32x4 acc11 = {0.f, 0.f, 0.f, 0.f};

  const int lrow = lane & 15;
  const int lk = (lane >> 4) * 8;

  for (int kb = 0; kb < 512; kb += 32) {
    __syncthreads();
    *(bf16x8*)&As[srow][skq * 8] =
        *(const bf16x8*)&A[(size_t)(mbase + srow) * 512 + kb + skq * 8];
    const float* wp = &W[(size_t)(nbase + srow) * 512 + kb + skq * 8];
    float4 w0 = *(const float4*)wp;
    float4 w1 = *(const float4*)(wp + 4);
    bf16x8 bv;
    bv[0] = (short)f2bf(w0.x); bv[1] = (short)f2bf(w0.y);
    bv[2] = (short)f2bf(w0.z); bv[3] = (short)f2bf(w0.w);
    bv[4] = (short)f2bf(w1.x); bv[5] = (short)f2bf(w1.y);
    bv[6] = (short)f2bf(w1.z); bv[7] = (short)f2bf(w1.w);
    *(bf16x8*)&Bs[srow][skq * 8] = bv;
    __syncthreads();

    bf16x8 a0 = *(const bf16x8*)&As[wr * 32 + lrow][lk];
    bf16x8 a1 = *(const bf16x8*)&As[wr * 32 + 16 + lrow][lk];
    bf16x8 b0 = *(const bf16x8*)&Bs[wc * 32 + lrow][lk];
    bf16x8 b1 = *(const bf16x8*)&Bs[wc * 32 + 16 + lrow][lk];
    acc00 = __builtin_amdgcn_mfma_f32_16x16x32_bf16(a0, b0, acc00, 0, 0, 0);
    acc01 = __builtin_amdgcn_mfma_f32_16x16x32_bf16(a0, b1, acc01, 0, 0, 0);
    acc10 = __builtin_amdgcn_mfma_f32_16x16x32_bf16(a1, b0, acc10, 0, 0, 0);
    acc11 = __builtin_amdgcn_mfma_f32_16x16x32_bf16(a1, b1, acc11, 0, 0, 0);
  }

  const int row0 = mbase + wr * 32 + (lane >> 4) * 4;
  const int col0 = nbase + wc * 32 + lrow;
#pragma unroll
  for (int ni = 0; ni < 2; ++ni) {
    int col = col0 + ni * 16;
    float bv = bias[col];
    const f32x4* a0p = (ni == 0) ? &acc00 : &acc01;
    const f32x4* a1p = (ni == 0) ? &acc10 : &acc11;
#pragma unroll
    for (int q = 0; q < 4; ++q) {
      float v0 = (*a0p)[q] + bv;
      out[(size_t)(row0 + q) * 256 + col] = fmaxf(v0, 0.0f);
      float v1 = (*a1p)[q] + bv;
      out[(size_t)(row0 + 16 + q) * 256 + col] = fmaxf(v1, 0.0f);
    }
  }
}

extern "C" void kernel_launch(void* const* d_in, const int* in_sizes, int n_in,
                              void* d_out, int out_size, void* d_ws, size_t ws_size,
                              hipStream_t stream) {
  // inputs: 0=h (unused), 1=positions, 2=past_positions, 3=W_emb, 4=b_emb
  const float2* pos = (const float2*)d_in[1];
  const float2* past = (const float2*)d_in[2];
  const float* W = (const float*)d_in[3];
  const float* bias = (const float*)d_in[4];
  float* out = (float*)d_out;

  unsigned short* gridws = (unsigned short*)d_ws;  // 4 MB bf16 [NP][512]

  pool_kernel<<<NP / IB, 256, 0, stream>>>(pos, past, gridws);
  dim3 g(256 / 64, NP / 64);
  gemm_kernel<<<g, 256, 0, stream>>>(gridws, W, bias, out);
}